// Round 2
// baseline (183.003 us; speedup 1.0000x reference)
//
#include <hip/hip_runtime.h>
#include <stdint.h>
#include <math.h>

#define SEQ 2048
#define NH 16
#define DM 1024

typedef __bf16 bf16x8 __attribute__((ext_vector_type(8)));
typedef __bf16 bf16x2 __attribute__((ext_vector_type(2)));
typedef short s16x4 __attribute__((ext_vector_type(4)));
typedef short s16x8 __attribute__((ext_vector_type(8)));
typedef float f32x4 __attribute__((ext_vector_type(4)));
typedef float f32x2 __attribute__((ext_vector_type(2)));

#define ASM_VMCNT0  asm volatile("s_waitcnt vmcnt(0)" ::: "memory")
#define ASM_BARRIER asm volatile("s_barrier" ::: "memory")

__device__ __forceinline__ unsigned short f2bf(float f) {
  union { float f; unsigned u; } v; v.f = f;
  unsigned r = v.u + 0x7fffu + ((v.u >> 16) & 1u);
  return (unsigned short)(r >> 16);
}
__device__ __forceinline__ unsigned pk2(float a, float b) {
  f32x2 v = {a, b};
  bf16x2 r = __builtin_convertvector(v, bf16x2);  // v_cvt_pk_bf16_f32
  union { bf16x2 h; unsigned u; } c; c.h = r;
  return c.u;
}
__device__ __forceinline__ void load_lds16(const void* g, void* l) {
  __builtin_amdgcn_global_load_lds((__attribute__((address_space(1))) void*)g,
                                   (__attribute__((address_space(3))) void*)l,
                                   16, 0, 0);
}

// ---------------------------------------------------------------------------
// fp32 -> bf16 conversion: x (4M) + wq/wk/wv/wo (1M each) into ws.
// ---------------------------------------------------------------------------
__global__ void cvt_all(const float* __restrict__ x, const float* __restrict__ wq,
                        const float* __restrict__ wk, const float* __restrict__ wv,
                        const float* __restrict__ wo, unsigned short* __restrict__ ws) {
  const int i = blockIdx.x * blockDim.x + threadIdx.x;
  const int off = i * 4;
  const float* src;
  unsigned short* dst;
  if (off < 4194304) {
    src = x + off;  dst = ws + off;
  } else {
    const int r = off - 4194304;
    const int w = r >> 20, o = r & 1048575;
    const float* tabs[4] = {wq, wk, wv, wo};
    src = tabs[w] + o;  dst = ws + 4194304 + (w << 20) + o;
  }
  const float4 v = *(const float4*)src;
  uint2 u;
  u.x = pk2(v.x, v.y);
  u.y = pk2(v.z, v.w);
  *(uint2*)dst = u;
}

// ---------------------------------------------------------------------------
// Fused QKV projection: C = x (4096x1024) @ W3^T (W3 = [wq;wk;wv], 3072x1024).
// 128x128 tiles, grid (24,32) = 768 blocks; 3 blocks/CU.
// V epilogue writes the key dim PERMUTED within each 64-block:
//   key = nb*16 + quad*4 + j  ->  g = quad*16 + (nb>>1)*8 + (nb&1)*4 + j
// so flash PV A-fragments (4 keys/lane, 2 nb per 16B) are b128-loadable.
// ---------------------------------------------------------------------------
__launch_bounds__(256, 3)
__global__ void gemm_qkv(const unsigned short* __restrict__ X,
                         const unsigned short* __restrict__ W3,
                         unsigned short* __restrict__ Qr,
                         unsigned short* __restrict__ Kr,
                         unsigned short* __restrict__ Vt,
                         const int* __restrict__ tp) {
  __shared__ __align__(16) char smem[32768];

  const int t = threadIdx.x;
  const int lane = t & 63, wave = t >> 6;
  const int quad = lane >> 4, l16 = lane & 15;
  const int m0 = blockIdx.y * 128, n0 = blockIdx.x * 128;
  const int wm = (wave >> 1) * 64, wn = (wave & 1) * 64;

  f32x4 acc[4][4];
#pragma unroll
  for (int i = 0; i < 4; i++)
#pragma unroll
    for (int j = 0; j < 4; j++) { acc[i][j][0]=0.f; acc[i][j][1]=0.f; acc[i][j][2]=0.f; acc[i][j][3]=0.f; }

  const int rr = t >> 2;
  const int cc = (t & 3) * 8;

#define QKV_STAGE(bufidx, k0_) do {                                               \
    char* a_ = smem + (bufidx) * 8192;                                            \
    char* b_ = smem + 16384 + (bufidx) * 8192;                                    \
    _Pragma("unroll")                                                             \
    for (int i_ = 0; i_ < 2; i_++) {                                              \
      load_lds16(X  + (uint64_t)(m0 + i_ * 64 + rr) * 1024 + (k0_) + cc,          \
                 a_ + i_ * 4096 + wave * 1024);                                   \
      load_lds16(W3 + (uint64_t)(n0 + i_ * 64 + rr) * 1024 + (k0_) + cc,          \
                 b_ + i_ * 4096 + wave * 1024);                                   \
    }                                                                             \
  } while (0)

  QKV_STAGE(0, 0);

  for (int k0 = 0; k0 < 1024; k0 += 32) {
    const int buf = (k0 >> 5) & 1;
    ASM_VMCNT0;
    ASM_BARRIER;
    if (k0 + 32 < 1024) QKV_STAGE(buf ^ 1, k0 + 32);
    char* As = smem + buf * 8192;
    char* Bs = smem + 16384 + buf * 8192;

    bf16x8 af[4], bfr[4];
#pragma unroll
    for (int i = 0; i < 4; i++) {
      af[i]  = *(const bf16x8*)(As + (wm + i * 16 + l16) * 64 + quad * 16);
      bfr[i] = *(const bf16x8*)(Bs + (wn + i * 16 + l16) * 64 + quad * 16);
    }
#pragma unroll
    for (int i = 0; i < 4; i++)
#pragma unroll
      for (int j = 0; j < 4; j++)
        acc[i][j] = __builtin_amdgcn_mfma_f32_16x16x32_bf16(af[i], bfr[j], acc[i][j], 0, 0, 0);
  }
#undef QKV_STAGE

  if (n0 < 2048) {
    unsigned short* dst = (n0 < 1024) ? Qr : Kr;
    float fr[4]; int dd[4], hh[4];
#pragma unroll
    for (int j = 0; j < 4; j++) {
      const int n = n0 + wn + j * 16 + l16;
      dd[j] = n & 63;
      hh[j] = (n & 1023) >> 6;
      fr[j] = __builtin_amdgcn_exp2f(-0.20762050594f * (float)(dd[j] & ~1)) * 0.15915494309f;
    }
    const float sgnodd = (l16 & 1) ? 1.f : -1.f;
#pragma unroll
    for (int i = 0; i < 4; i++) {
#pragma unroll
      for (int r = 0; r < 4; r++) {
        const int m = m0 + wm + i * 16 + quad * 4 + r;
        const int s = m & 2047, b = m >> 11;
        const float posf = (float)tp[m];
#pragma unroll
        for (int j = 0; j < 4; j++) {
          const float v = acc[i][j][r];
          const float p = __shfl_xor(v, 1);
          float rev = posf * fr[j];
          rev -= floorf(rev);
          float sn, cs;
          asm("v_sin_f32 %0, %1" : "=v"(sn) : "v"(rev));
          asm("v_cos_f32 %0, %1" : "=v"(cs) : "v"(rev));
          const float rv = fmaf(v, cs, p * sn * sgnodd);
          dst[((uint64_t)((b * NH + hh[j]) * SEQ + s)) * 64 + dd[j]] = f2bf(rv);
        }
      }
    }
  } else {
    // V -> Vt (b,h,d,s_permuted): 4 consecutive s (=j) share (quad_v, nb_v).
#pragma unroll
    for (int i = 0; i < 4; i++) {
      const int m = m0 + wm + i * 16 + quad * 4;
      const int s = m & 2047, b = m >> 11;
      const int sl = s & 63;
      const int qv = (sl >> 2) & 3, nv = sl >> 4;
      const int g = (s & ~63) + qv * 16 + (nv >> 1) * 8 + (nv & 1) * 4;
#pragma unroll
      for (int j = 0; j < 4; j++) {
        const int n = n0 - 2048 + wn + j * 16 + l16;
        const int h = n >> 6, d = n & 63;
        uint2 w;
        w.x = pk2(acc[i][j][0], acc[i][j][1]);
        w.y = pk2(acc[i][j][2], acc[i][j][3]);
        *(uint2*)(Vt + ((uint64_t)((b * NH + h) * 64 + d)) * SEQ + g) = w;
      }
    }
  }
}

// ---------------------------------------------------------------------------
// Output projection: C = At (4096x1024) @ wo^T, fp32 out. 128x128 tiles,
// grid (8,32) = 256 blocks (1/CU, uniform). 2x MFMA per staged byte vs 128x64.
// ---------------------------------------------------------------------------
__launch_bounds__(256, 2)
__global__ void gemm_ao(const unsigned short* __restrict__ A,
                        const unsigned short* __restrict__ B,
                        float* __restrict__ C) {
  __shared__ __align__(16) char smem[32768];

  const int t = threadIdx.x;
  const int lane = t & 63, wave = t >> 6;
  const int quad = lane >> 4, l16 = lane & 15;
  const int m0 = blockIdx.y * 128, n0 = blockIdx.x * 128;
  const int wm = (wave >> 1) * 64, wn = (wave & 1) * 64;

  f32x4 acc[4][4];
#pragma unroll
  for (int i = 0; i < 4; i++)
#pragma unroll
    for (int j = 0; j < 4; j++) { acc[i][j][0]=0.f; acc[i][j][1]=0.f; acc[i][j][2]=0.f; acc[i][j][3]=0.f; }

  const int rr = t >> 2;
  const int cc = (t & 3) * 8;

#define AO_STAGE(bufidx, k0_) do {                                               \
    char* a_ = smem + (bufidx) * 8192;                                            \
    char* b_ = smem + 16384 + (bufidx) * 8192;                                    \
    _Pragma("unroll")                                                             \
    for (int i_ = 0; i_ < 2; i_++) {                                              \
      load_lds16(A + (uint64_t)(m0 + i_ * 64 + rr) * 1024 + (k0_) + cc,           \
                 a_ + i_ * 4096 + wave * 1024);                                   \
      load_lds16(B + (uint64_t)(n0 + i_ * 64 + rr) * 1024 + (k0_) + cc,           \
                 b_ + i_ * 4096 + wave * 1024);                                   \
    }                                                                             \
  } while (0)

  AO_STAGE(0, 0);

  for (int k0 = 0; k0 < 1024; k0 += 32) {
    const int buf = (k0 >> 5) & 1;
    ASM_VMCNT0;
    ASM_BARRIER;
    if (k0 + 32 < 1024) AO_STAGE(buf ^ 1, k0 + 32);
    char* As = smem + buf * 8192;
    char* Bs = smem + 16384 + buf * 8192;

    bf16x8 af[4], bfr[4];
#pragma unroll
    for (int i = 0; i < 4; i++) {
      af[i]  = *(const bf16x8*)(As + (wm + i * 16 + l16) * 64 + quad * 16);
      bfr[i] = *(const bf16x8*)(Bs + (wn + i * 16 + l16) * 64 + quad * 16);
    }
#pragma unroll
    for (int i = 0; i < 4; i++)
#pragma unroll
      for (int j = 0; j < 4; j++)
        acc[i][j] = __builtin_amdgcn_mfma_f32_16x16x32_bf16(af[i], bfr[j], acc[i][j], 0, 0, 0);
  }
#undef AO_STAGE

#pragma unroll
  for (int i = 0; i < 4; i++)
#pragma unroll
    for (int j = 0; j < 4; j++)
#pragma unroll
      for (int r = 0; r < 4; r++) {
        const int m = m0 + wm + i * 16 + quad * 4 + r;
        const int n = n0 + wn + j * 16 + l16;
        C[(uint64_t)m * DM + n] = acc[i][j][r];
      }
}

// ---------------------------------------------------------------------------
// Flash attention r11: 256 blocks x 512 threads (8 waves). Block = one bh
// plane + causal tile PAIR (a, 15-a), but the pair now runs CONCURRENTLY:
//   waves 0-3 (group 0) own Q-tile a       (ng0 = 2a+2  k-tiles)
//   waves 4-7 (group 1) own Q-tile 15-a    (ng1 = 32-2a k-tiles)
// Each wave computes 32 q rows (two 16-q subgroups) so every K/V fragment
// ds_read feeds 2 (QK) or 4 (PV) MFMAs -> LDS reads per unit work HALVE
// (R1 post-mortem: 128 b128/iter ~ 1536cy was 53% of the iteration; counted
// vmcnt was neutral because loads complete early -> LDS BW is the floor).
// Per-block LDS cost = (ng0+ng1) = 34 half-cost tile-steps, identical for
// every a -> balanced grid. Each group double-buffers its own 16KB K+V
// (64KB LDS total); all 512 threads cooperatively stage both groups' tiles.
// ---------------------------------------------------------------------------
__launch_bounds__(512, 2)
__global__ void flash_attn(const unsigned short* __restrict__ Q,
                           const unsigned short* __restrict__ K,
                           const unsigned short* __restrict__ Vt,
                           unsigned short* __restrict__ Oa) {
  __shared__ __align__(16) char smem[65536];
  // group g: K at g*32768 + buf*16384, V at +8192

  const int t = threadIdx.x;
  const int lane = t & 63, wave = t >> 6;    // wave = 0..7
  const int quad = lane >> 4, l16 = lane & 15;
  const int g = wave >> 2, wv = wave & 3;
  const int lid = blockIdx.x;
  const int bh = lid & 31;
  const int a = lid >> 5;                    // 0..7 -> tile pair (a, 15-a)
  const uint64_t base = (uint64_t)bh * (SEQ * 64);
  const int qb = (g ? (15 - a) : a) * 128;
  const int ng0 = 2 * a + 2, ng1 = 32 - 2 * a;   // k-tiles per group
  const int ngMy = g ? ng1 : ng0;
  const int qlo = qb + wv * 32;              // wave's 32-q range start
  const int qg0 = qlo + l16;                 // subgroup-0 q row
  const int qg1 = qlo + 16 + l16;            // subgroup-1 q row
  const int b = bh >> 4, h = bh & 15;

  // Q B-fragments for both subgroups (n=q=l16, k=d=kk*32+quad*8+j)
  bf16x8 qf[2][2];
  {
    const unsigned short* qp0 = Q + base + (uint64_t)qg0 * 64 + quad * 8;
    qf[0][0] = *(const bf16x8*)qp0;  qf[0][1] = *(const bf16x8*)(qp0 + 32);
    const unsigned short* qp1 = Q + base + (uint64_t)qg1 * 64 + quad * 8;
    qf[1][0] = *(const bf16x8*)qp1;  qf[1][1] = *(const bf16x8*)(qp1 + 32);
  }

  f32x4 o0[4], o1[4];
#pragma unroll
  for (int i = 0; i < 4; i++) {
    o0[i][0]=0.f; o0[i][1]=0.f; o0[i][2]=0.f; o0[i][3]=0.f;
    o1[i][0]=0.f; o1[i][1]=0.f; o1[i][2]=0.f; o1[i][3]=0.f;
  }
  float lI0 = 0.f, lI1 = 0.f;

  // staging: 512 threads cover a 64-row x 128B tile in one call.
  // LDS chunk c at row r holds global 16B-chunk c ^ (r&7).
  const int srow = wave * 8 + (lane >> 3);
  const int sc = ((lane & 7) ^ ((lane >> 3) & 7)) * 8;   // shorts
  const int swz = (l16 & 7);

#define STAGE(gg, bufidx, kb_) do {                                               \
    load_lds16(K  + base + (uint64_t)((kb_) + srow) * 64 + sc,                    \
               smem + (gg) * 32768 + (bufidx) * 16384 + wave * 1024);             \
    load_lds16(Vt + base + (uint64_t)srow * SEQ + (kb_) + sc,                     \
               smem + (gg) * 32768 + (bufidx) * 16384 + 8192 + wave * 1024);      \
  } while (0)

  STAGE(0, 0, 0);
  STAGE(1, 0, 0);

  const float c1 = 0.18033688011f;  // log2(e)/8
  const int nIt = ng1;              // ng1 >= ng0 always (a <= 7)

  for (int it = 0; it < nIt; it++) {
    const int buf = it & 1;
    ASM_VMCNT0;     // stage(it) loads (issued last iter) are long done
    ASM_BARRIER;
    const int itn = it + 1;
    if (itn < ng0) STAGE(0, itn & 1, itn * 64);
    if (itn < ng1) STAGE(1, itn & 1, itn * 64);

    if (it < ngMy) {
      const int kb = it * 64;
      char* ks = smem + g * 32768 + buf * 16384;
      char* vs = ks + 8192;

      int nbmax = ((qlo + 31 - kb) >> 4) + 1;
      nbmax = nbmax > 4 ? 4 : (nbmax < 0 ? 0 : nbmax);
      const bool diag = (kb + 63) > qlo;   // wave-uniform

      // S^T = K Q^T : key = kb + nb*16 + quad*4 + r, q = l16 (per subgroup)
      f32x4 sf0[4], sf1[4];
      float ls0 = 0.f, ls1 = 0.f;
#pragma unroll
      for (int nb = 0; nb < 4; nb++) {
        if (nb < nbmax) {
          f32x4 s0; s0[0]=0.f; s0[1]=0.f; s0[2]=0.f; s0[3]=0.f;
          f32x4 s1; s1[0]=0.f; s1[1]=0.f; s1[2]=0.f; s1[3]=0.f;
#pragma unroll
          for (int kk = 0; kk < 2; kk++) {
            bf16x8 kfr = *(const bf16x8*)(ks + (nb * 16 + l16) * 128 + (((kk * 4 + quad) ^ swz) * 16));
            s0 = __builtin_amdgcn_mfma_f32_16x16x32_bf16(kfr, qf[0][kk], s0, 0, 0, 0);
            s1 = __builtin_amdgcn_mfma_f32_16x16x32_bf16(kfr, qf[1][kk], s1, 0, 0, 0);
          }
          if (diag) {
#pragma unroll
            for (int r = 0; r < 4; r++) {
              const int key = kb + nb * 16 + quad * 4 + r;
              const float p0 = (key <= qg0) ? __builtin_amdgcn_exp2f(s0[r] * c1) : 0.f;
              sf0[nb][r] = p0;  ls0 += p0;
              const float p1 = (key <= qg1) ? __builtin_amdgcn_exp2f(s1[r] * c1) : 0.f;
              sf1[nb][r] = p1;  ls1 += p1;
            }
          } else {
#pragma unroll
            for (int r = 0; r < 4; r++) {
              const float p0 = __builtin_amdgcn_exp2f(s0[r] * c1);
              sf0[nb][r] = p0;  ls0 += p0;
              const float p1 = __builtin_amdgcn_exp2f(s1[r] * c1);
              sf1[nb][r] = p1;  ls1 += p1;
            }
          }
        }
      }
      lI0 += ls0;  lI1 += ls1;

      // PV: P in regs; V-frag pair (nb=2np, 2np+1) in ONE b128 from permuted
      // V layout; each V fragment feeds BOTH subgroups (4 MFMA per read).
#pragma unroll
      for (int np = 0; np < 2; np++) {
        if (2 * np < nbmax) {
          union { uint2 u; s16x4 h; } a0, b0, a1, b1;
          a0.u.x = pk2(sf0[2 * np][0], sf0[2 * np][1]);
          a0.u.y = pk2(sf0[2 * np][2], sf0[2 * np][3]);
          b0.u.x = pk2(sf1[2 * np][0], sf1[2 * np][1]);
          b0.u.y = pk2(sf1[2 * np][2], sf1[2 * np][3]);
          const bool hi = (2 * np + 1 < nbmax);
          if (hi) {
            a1.u.x = pk2(sf0[2 * np + 1][0], sf0[2 * np + 1][1]);
            a1.u.y = pk2(sf0[2 * np + 1][2], sf0[2 * np + 1][3]);
            b1.u.x = pk2(sf1[2 * np + 1][0], sf1[2 * np + 1][1]);
            b1.u.y = pk2(sf1[2 * np + 1][2], sf1[2 * np + 1][3]);
          }
#pragma unroll
          for (int db = 0; db < 4; db++) {
            s16x8 vv = *(const s16x8*)(vs + (db * 16 + l16) * 128 +
                                       (((quad * 2 + np) ^ swz) * 16));
            s16x4 vlo = __builtin_shufflevector(vv, vv, 0, 1, 2, 3);
            o0[db] = __builtin_amdgcn_mfma_f32_16x16x16bf16_1k(vlo, a0.h, o0[db], 0, 0, 0);
            o1[db] = __builtin_amdgcn_mfma_f32_16x16x16bf16_1k(vlo, b0.h, o1[db], 0, 0, 0);
            if (hi) {
              s16x4 vhi = __builtin_shufflevector(vv, vv, 4, 5, 6, 7);
              o0[db] = __builtin_amdgcn_mfma_f32_16x16x16bf16_1k(vhi, a1.h, o0[db], 0, 0, 0);
              o1[db] = __builtin_amdgcn_mfma_f32_16x16x16bf16_1k(vhi, b1.h, o1[db], 0, 0, 0);
            }
          }
        }
      }

      if (it == ngMy - 1) {
        // my group's tile is done: reduce l across quads, normalize, store
        float lr0 = lI0;
        lr0 += __shfl_xor(lr0, 16);
        lr0 += __shfl_xor(lr0, 32);
        const float il0 = 1.0f / lr0;
        float lr1 = lI1;
        lr1 += __shfl_xor(lr1, 16);
        lr1 += __shfl_xor(lr1, 32);
        const float il1 = 1.0f / lr1;
        unsigned short* p0r = Oa + ((uint64_t)(b * SEQ + qg0)) * DM + h * 64 + quad * 4;
        unsigned short* p1r = Oa + ((uint64_t)(b * SEQ + qg1)) * DM + h * 64 + quad * 4;
#pragma unroll
        for (int db = 0; db < 4; db++) {
          uint2 w;
          w.x = pk2(o0[db][0] * il0, o0[db][1] * il0);
          w.y = pk2(o0[db][2] * il0, o0[db][3] * il0);
          *(uint2*)(p0r + db * 16) = w;
          w.x = pk2(o1[db][0] * il1, o1[db][1] * il1);
          w.y = pk2(o1[db][2] * il1, o1[db][3] * il1);
          *(uint2*)(p1r + db * 16) = w;
        }
      }
    }
  }
#undef STAGE
}

extern "C" void kernel_launch(void* const* d_in, const int* in_sizes, int n_in,
                              void* d_out, int out_size, void* d_ws, size_t ws_size,
                              hipStream_t stream) {
  const float* x  = (const float*)d_in[0];
  const int* tp   = (const int*)d_in[1];
  const float* wq = (const float*)d_in[2];
  const float* wk = (const float*)d_in[3];
  const float* wv = (const float*)d_in[4];
  const float* wo = (const float*)d_in[5];
  float* out = (float*)d_out;

  unsigned short* ws = (unsigned short*)d_ws;
  unsigned short* xb  = ws;                   // (b,s,dm) bf16        8 MB
  unsigned short* w3b = ws + 4194304;         // [wq;wk;wv] 3072x1024 6 MB
  unsigned short* wob = ws + 7340032;         // 2 MB
  unsigned short* Qr  = ws + 8388608;         // (b,h,s,64)  8 MB
  unsigned short* Kr  = ws + 12582912;        // (b,h,s,64)  8 MB
  unsigned short* Vt  = ws + 16777216;        // (b,h,64,s-perm)  8 MB
  unsigned short* At  = ws + 20971520;        // (b,s,h*64)  8 MB

  cvt_all<<<8192, 256, 0, stream>>>(x, wq, wk, wv, wo, ws);
  gemm_qkv<<<dim3(24, 32), 256, 0, stream>>>(xb, w3b, Qr, Kr, Vt, tp);
  flash_attn<<<256, 512, 0, stream>>>(Qr, Kr, Vt, At);
  gemm_ao<<<dim3(8, 32), 256, 0, stream>>>(At, wob, out);
}

// Round 3
// 174.239 us; speedup vs baseline: 1.0503x; 1.0503x over previous
//
#include <hip/hip_runtime.h>
#include <stdint.h>
#include <math.h>

#define SEQ 2048
#define NH 16
#define DM 1024

typedef __bf16 bf16x8 __attribute__((ext_vector_type(8)));
typedef __bf16 bf16x2 __attribute__((ext_vector_type(2)));
typedef short s16x4 __attribute__((ext_vector_type(4)));
typedef short s16x8 __attribute__((ext_vector_type(8)));
typedef float f32x4 __attribute__((ext_vector_type(4)));
typedef float f32x2 __attribute__((ext_vector_type(2)));

#define ASM_VMCNT0  asm volatile("s_waitcnt vmcnt(0)" ::: "memory")
#define ASM_BARRIER asm volatile("s_barrier" ::: "memory")

__device__ __forceinline__ unsigned short f2bf(float f) {
  union { float f; unsigned u; } v; v.f = f;
  unsigned r = v.u + 0x7fffu + ((v.u >> 16) & 1u);
  return (unsigned short)(r >> 16);
}
__device__ __forceinline__ unsigned pk2(float a, float b) {
  f32x2 v = {a, b};
  bf16x2 r = __builtin_convertvector(v, bf16x2);  // v_cvt_pk_bf16_f32
  union { bf16x2 h; unsigned u; } c; c.h = r;
  return c.u;
}
__device__ __forceinline__ void load_lds16(const void* g, void* l) {
  __builtin_amdgcn_global_load_lds((__attribute__((address_space(1))) void*)g,
                                   (__attribute__((address_space(3))) void*)l,
                                   16, 0, 0);
}

// ---------------------------------------------------------------------------
// fp32 -> bf16 conversion: x (4M) + wq/wk/wv/wo (1M each) into ws.
// ---------------------------------------------------------------------------
__global__ void cvt_all(const float* __restrict__ x, const float* __restrict__ wq,
                        const float* __restrict__ wk, const float* __restrict__ wv,
                        const float* __restrict__ wo, unsigned short* __restrict__ ws) {
  const int i = blockIdx.x * blockDim.x + threadIdx.x;
  const int off = i * 4;
  const float* src;
  unsigned short* dst;
  if (off < 4194304) {
    src = x + off;  dst = ws + off;
  } else {
    const int r = off - 4194304;
    const int w = r >> 20, o = r & 1048575;
    const float* tabs[4] = {wq, wk, wv, wo};
    src = tabs[w] + o;  dst = ws + 4194304 + (w << 20) + o;
  }
  const float4 v = *(const float4*)src;
  uint2 u;
  u.x = pk2(v.x, v.y);
  u.y = pk2(v.z, v.w);
  *(uint2*)dst = u;
}

// ---------------------------------------------------------------------------
// Fused QKV projection: C = x (4096x1024) @ W3^T (W3 = [wq;wk;wv], 3072x1024).
// 128x128 tiles, grid (24,32) = 768 blocks; 3 blocks/CU.
// V epilogue writes the key dim PERMUTED within each 64-block:
//   key = nb*16 + quad*4 + j  ->  g = quad*16 + (nb>>1)*8 + (nb&1)*4 + j
// so flash PV A-fragments (4 keys/lane, 2 nb per 16B) are b128-loadable.
// ---------------------------------------------------------------------------
__launch_bounds__(256, 3)
__global__ void gemm_qkv(const unsigned short* __restrict__ X,
                         const unsigned short* __restrict__ W3,
                         unsigned short* __restrict__ Qr,
                         unsigned short* __restrict__ Kr,
                         unsigned short* __restrict__ Vt,
                         const int* __restrict__ tp) {
  __shared__ __align__(16) char smem[32768];

  const int t = threadIdx.x;
  const int lane = t & 63, wave = t >> 6;
  const int quad = lane >> 4, l16 = lane & 15;
  const int m0 = blockIdx.y * 128, n0 = blockIdx.x * 128;
  const int wm = (wave >> 1) * 64, wn = (wave & 1) * 64;

  f32x4 acc[4][4];
#pragma unroll
  for (int i = 0; i < 4; i++)
#pragma unroll
    for (int j = 0; j < 4; j++) { acc[i][j][0]=0.f; acc[i][j][1]=0.f; acc[i][j][2]=0.f; acc[i][j][3]=0.f; }

  const int rr = t >> 2;
  const int cc = (t & 3) * 8;

#define QKV_STAGE(bufidx, k0_) do {                                               \
    char* a_ = smem + (bufidx) * 8192;                                            \
    char* b_ = smem + 16384 + (bufidx) * 8192;                                    \
    _Pragma("unroll")                                                             \
    for (int i_ = 0; i_ < 2; i_++) {                                              \
      load_lds16(X  + (uint64_t)(m0 + i_ * 64 + rr) * 1024 + (k0_) + cc,          \
                 a_ + i_ * 4096 + wave * 1024);                                   \
      load_lds16(W3 + (uint64_t)(n0 + i_ * 64 + rr) * 1024 + (k0_) + cc,          \
                 b_ + i_ * 4096 + wave * 1024);                                   \
    }                                                                             \
  } while (0)

  QKV_STAGE(0, 0);

  for (int k0 = 0; k0 < 1024; k0 += 32) {
    const int buf = (k0 >> 5) & 1;
    ASM_VMCNT0;
    ASM_BARRIER;
    if (k0 + 32 < 1024) QKV_STAGE(buf ^ 1, k0 + 32);
    char* As = smem + buf * 8192;
    char* Bs = smem + 16384 + buf * 8192;

    bf16x8 af[4], bfr[4];
#pragma unroll
    for (int i = 0; i < 4; i++) {
      af[i]  = *(const bf16x8*)(As + (wm + i * 16 + l16) * 64 + quad * 16);
      bfr[i] = *(const bf16x8*)(Bs + (wn + i * 16 + l16) * 64 + quad * 16);
    }
#pragma unroll
    for (int i = 0; i < 4; i++)
#pragma unroll
      for (int j = 0; j < 4; j++)
        acc[i][j] = __builtin_amdgcn_mfma_f32_16x16x32_bf16(af[i], bfr[j], acc[i][j], 0, 0, 0);
  }
#undef QKV_STAGE

  if (n0 < 2048) {
    unsigned short* dst = (n0 < 1024) ? Qr : Kr;
    float fr[4]; int dd[4], hh[4];
#pragma unroll
    for (int j = 0; j < 4; j++) {
      const int n = n0 + wn + j * 16 + l16;
      dd[j] = n & 63;
      hh[j] = (n & 1023) >> 6;
      fr[j] = __builtin_amdgcn_exp2f(-0.20762050594f * (float)(dd[j] & ~1)) * 0.15915494309f;
    }
    const float sgnodd = (l16 & 1) ? 1.f : -1.f;
#pragma unroll
    for (int i = 0; i < 4; i++) {
#pragma unroll
      for (int r = 0; r < 4; r++) {
        const int m = m0 + wm + i * 16 + quad * 4 + r;
        const int s = m & 2047, b = m >> 11;
        const float posf = (float)tp[m];
#pragma unroll
        for (int j = 0; j < 4; j++) {
          const float v = acc[i][j][r];
          const float p = __shfl_xor(v, 1);
          float rev = posf * fr[j];
          rev -= floorf(rev);
          float sn, cs;
          asm("v_sin_f32 %0, %1" : "=v"(sn) : "v"(rev));
          asm("v_cos_f32 %0, %1" : "=v"(cs) : "v"(rev));
          const float rv = fmaf(v, cs, p * sn * sgnodd);
          dst[((uint64_t)((b * NH + hh[j]) * SEQ + s)) * 64 + dd[j]] = f2bf(rv);
        }
      }
    }
  } else {
    // V -> Vt (b,h,d,s_permuted): 4 consecutive s (=j) share (quad_v, nb_v).
#pragma unroll
    for (int i = 0; i < 4; i++) {
      const int m = m0 + wm + i * 16 + quad * 4;
      const int s = m & 2047, b = m >> 11;
      const int sl = s & 63;
      const int qv = (sl >> 2) & 3, nv = sl >> 4;
      const int g = (s & ~63) + qv * 16 + (nv >> 1) * 8 + (nv & 1) * 4;
#pragma unroll
      for (int j = 0; j < 4; j++) {
        const int n = n0 - 2048 + wn + j * 16 + l16;
        const int h = n >> 6, d = n & 63;
        uint2 w;
        w.x = pk2(acc[i][j][0], acc[i][j][1]);
        w.y = pk2(acc[i][j][2], acc[i][j][3]);
        *(uint2*)(Vt + ((uint64_t)((b * NH + h) * 64 + d)) * SEQ + g) = w;
      }
    }
  }
}

// ---------------------------------------------------------------------------
// Output projection: C = At (4096x1024) @ wo^T, fp32 out. 128x128 tiles,
// grid (8,32) = 256 blocks (1/CU, uniform). 2x MFMA per staged byte vs 128x64.
// ---------------------------------------------------------------------------
__launch_bounds__(256, 2)
__global__ void gemm_ao(const unsigned short* __restrict__ A,
                        const unsigned short* __restrict__ B,
                        float* __restrict__ C) {
  __shared__ __align__(16) char smem[32768];

  const int t = threadIdx.x;
  const int lane = t & 63, wave = t >> 6;
  const int quad = lane >> 4, l16 = lane & 15;
  const int m0 = blockIdx.y * 128, n0 = blockIdx.x * 128;
  const int wm = (wave >> 1) * 64, wn = (wave & 1) * 64;

  f32x4 acc[4][4];
#pragma unroll
  for (int i = 0; i < 4; i++)
#pragma unroll
    for (int j = 0; j < 4; j++) { acc[i][j][0]=0.f; acc[i][j][1]=0.f; acc[i][j][2]=0.f; acc[i][j][3]=0.f; }

  const int rr = t >> 2;
  const int cc = (t & 3) * 8;

#define AO_STAGE(bufidx, k0_) do {                                               \
    char* a_ = smem + (bufidx) * 8192;                                            \
    char* b_ = smem + 16384 + (bufidx) * 8192;                                    \
    _Pragma("unroll")                                                             \
    for (int i_ = 0; i_ < 2; i_++) {                                              \
      load_lds16(A + (uint64_t)(m0 + i_ * 64 + rr) * 1024 + (k0_) + cc,           \
                 a_ + i_ * 4096 + wave * 1024);                                   \
      load_lds16(B + (uint64_t)(n0 + i_ * 64 + rr) * 1024 + (k0_) + cc,           \
                 b_ + i_ * 4096 + wave * 1024);                                   \
    }                                                                             \
  } while (0)

  AO_STAGE(0, 0);

  for (int k0 = 0; k0 < 1024; k0 += 32) {
    const int buf = (k0 >> 5) & 1;
    ASM_VMCNT0;
    ASM_BARRIER;
    if (k0 + 32 < 1024) AO_STAGE(buf ^ 1, k0 + 32);
    char* As = smem + buf * 8192;
    char* Bs = smem + 16384 + buf * 8192;

    bf16x8 af[4], bfr[4];
#pragma unroll
    for (int i = 0; i < 4; i++) {
      af[i]  = *(const bf16x8*)(As + (wm + i * 16 + l16) * 64 + quad * 16);
      bfr[i] = *(const bf16x8*)(Bs + (wn + i * 16 + l16) * 64 + quad * 16);
    }
#pragma unroll
    for (int i = 0; i < 4; i++)
#pragma unroll
      for (int j = 0; j < 4; j++)
        acc[i][j] = __builtin_amdgcn_mfma_f32_16x16x32_bf16(af[i], bfr[j], acc[i][j], 0, 0, 0);
  }
#undef AO_STAGE

#pragma unroll
  for (int i = 0; i < 4; i++)
#pragma unroll
    for (int j = 0; j < 4; j++)
#pragma unroll
      for (int r = 0; r < 4; r++) {
        const int m = m0 + wm + i * 16 + quad * 4 + r;
        const int n = n0 + wn + j * 16 + l16;
        C[(uint64_t)m * DM + n] = acc[i][j][r];
      }
}

// ---------------------------------------------------------------------------
// Flash attention r12: 1024 blocks x 256 threads (4 waves), 4 blocks/CU.
// R1/R2 post-mortem: sync relaxation (R1) and LDS-traffic halving (R2) were
// both neutral/negative at MfmaUtil 20 / VALUBusy 30 / occupancy 19% -> the
// kernel is LATENCY-bound on the per-wave chain (ds_read -> MFMA -> exp2 ->
// pack -> MFMA) with only 2 waves/SIMD. Fix = concurrency, not traffic:
// one 64-row Q-tile per block (wave = 16 q rows, the short proven chain),
// ng = tq+1 K-tile iterations, 32KB LDS dbuf -> 4 blocks/CU = 4 waves/SIMD,
// independent 4-wave barriers. Causal imbalance handled by launching big
// tiles first (tq = 31 - u/32); 1024 blocks over 256 CUs, mean 66
// iter-units/CU, short tail.
// ---------------------------------------------------------------------------
__launch_bounds__(256, 4)
__global__ void flash_attn(const unsigned short* __restrict__ Q,
                           const unsigned short* __restrict__ K,
                           const unsigned short* __restrict__ Vt,
                           unsigned short* __restrict__ Oa) {
  __shared__ __align__(16) char smem[32768];
  // K dbuf: 0 / 8192; V dbuf: 16384 / 24576

  const int t = threadIdx.x;
  const int lane = t & 63, wid = t >> 6;     // wid = 0..3
  const int quad = lane >> 4, l16 = lane & 15;
  const int u = blockIdx.x;
  const int tq = 31 - (u >> 5);              // Q-tile index, big tiles first
  const int bh = u & 31;
  const uint64_t base = (uint64_t)bh * (SEQ * 64);
  const int qb = tq * 64;
  const int ng = tq + 1;                     // K-tiles for this Q-tile
  const int qg = qb + wid * 16 + l16;        // this lane's q row
  const int b = bh >> 4, h = bh & 15;

  // Q B-fragment (n=q=l16, k=d=kk*32+quad*8+j)
  bf16x8 qf[2];
  {
    const unsigned short* qp = Q + base + (uint64_t)qg * 64 + quad * 8;
    qf[0] = *(const bf16x8*)qp;  qf[1] = *(const bf16x8*)(qp + 32);
  }

  f32x4 o[4];
#pragma unroll
  for (int i = 0; i < 4; i++) { o[i][0]=0.f; o[i][1]=0.f; o[i][2]=0.f; o[i][3]=0.f; }
  float lI = 0.f;

  // staging: 256 threads cover a 64-row x 128B tile in 2 calls/array.
  // LDS chunk c at row r holds global 16B-chunk c ^ (r&7).
  // row r = wid*16 + i*8 + (lane>>3); r&7 = lane>>3 (i*8 only sets bit 3).
  const int sr8 = lane >> 3;
  const int sc = ((lane & 7) ^ sr8) * 8;     // shorts
  const int swz = (l16 & 7);

#define STAGE(bufidx, kb_) do {                                                   \
    _Pragma("unroll")                                                             \
    for (int i_ = 0; i_ < 2; i_++) {                                              \
      const int r_ = wid * 16 + i_ * 8 + sr8;                                     \
      load_lds16(K  + base + (uint64_t)((kb_) + r_) * 64 + sc,                    \
                 smem + (bufidx) * 8192 + wid * 2048 + i_ * 1024);                \
      load_lds16(Vt + base + (uint64_t)r_ * SEQ + (kb_) + sc,                     \
                 smem + 16384 + (bufidx) * 8192 + wid * 2048 + i_ * 1024);        \
    }                                                                             \
  } while (0)

  STAGE(0, 0);

  const float c1 = 0.18033688011f;  // log2(e)/8

  for (int it = 0; it < ng; it++) {
    const int kb = it * 64;
    const int buf = it & 1;
    ASM_VMCNT0;     // stage(it) loads were issued a full iteration ago
    ASM_BARRIER;
    if (it + 1 < ng) STAGE(buf ^ 1, (it + 1) * 64);
    char* ks = smem + buf * 8192;
    char* vs = smem + 16384 + buf * 8192;

    int nbmax = ((qb + wid * 16 + 15 - kb) >> 4) + 1;
    nbmax = nbmax > 4 ? 4 : (nbmax < 0 ? 0 : nbmax);
    const bool diag = (kb + 63) > (qb + wid * 16);   // wave-uniform

    // S^T = K Q^T : key = kb + nb*16 + quad*4 + r, q = l16
    f32x4 sf[4];
    float ls = 0.f;
#pragma unroll
    for (int nb = 0; nb < 4; nb++) {
      if (nb < nbmax) {
        f32x4 s; s[0]=0.f; s[1]=0.f; s[2]=0.f; s[3]=0.f;
#pragma unroll
        for (int kk = 0; kk < 2; kk++) {
          bf16x8 kfr = *(const bf16x8*)(ks + (nb * 16 + l16) * 128 + (((kk * 4 + quad) ^ swz) * 16));
          s = __builtin_amdgcn_mfma_f32_16x16x32_bf16(kfr, qf[kk], s, 0, 0, 0);
        }
        if (diag) {
#pragma unroll
          for (int r = 0; r < 4; r++) {
            const int key = kb + nb * 16 + quad * 4 + r;
            const float p = (key <= qg) ? __builtin_amdgcn_exp2f(s[r] * c1) : 0.f;
            sf[nb][r] = p;  ls += p;
          }
        } else {
#pragma unroll
          for (int r = 0; r < 4; r++) {
            const float p = __builtin_amdgcn_exp2f(s[r] * c1);
            sf[nb][r] = p;  ls += p;
          }
        }
      }
    }
    lI += ls;   // lane-local partial (this quad's keys); reduced at epilogue

    // PV: P in regs; V-frag pair (nb=2np, 2np+1) in ONE b128 from permuted V.
#pragma unroll
    for (int np = 0; np < 2; np++) {
      if (2 * np < nbmax) {
        union { uint2 u; s16x4 h; } p0;
        p0.u.x = pk2(sf[2 * np][0], sf[2 * np][1]);
        p0.u.y = pk2(sf[2 * np][2], sf[2 * np][3]);
        const bool hi = (2 * np + 1 < nbmax);
        union { uint2 u; s16x4 h; } p1;
        if (hi) {
          p1.u.x = pk2(sf[2 * np + 1][0], sf[2 * np + 1][1]);
          p1.u.y = pk2(sf[2 * np + 1][2], sf[2 * np + 1][3]);
        }
#pragma unroll
        for (int db = 0; db < 4; db++) {
          s16x8 vv = *(const s16x8*)(vs + (db * 16 + l16) * 128 +
                                     (((quad * 2 + np) ^ swz) * 16));
          s16x4 vlo = __builtin_shufflevector(vv, vv, 0, 1, 2, 3);
          o[db] = __builtin_amdgcn_mfma_f32_16x16x16bf16_1k(vlo, p0.h, o[db], 0, 0, 0);
          if (hi) {
            s16x4 vhi = __builtin_shufflevector(vv, vv, 4, 5, 6, 7);
            o[db] = __builtin_amdgcn_mfma_f32_16x16x16bf16_1k(vhi, p1.h, o[db], 0, 0, 0);
          }
        }
      }
    }
  }
#undef STAGE

  // epilogue: reduce l across quads, normalize, store
  float lr = lI;
  lr += __shfl_xor(lr, 16);
  lr += __shfl_xor(lr, 32);
  const float invl = 1.0f / lr;
  unsigned short* orow = Oa + ((uint64_t)(b * SEQ + qg)) * DM + h * 64 + quad * 4;
#pragma unroll
  for (int db = 0; db < 4; db++) {
    uint2 w;
    w.x = pk2(o[db][0] * invl, o[db][1] * invl);
    w.y = pk2(o[db][2] * invl, o[db][3] * invl);
    *(uint2*)(orow + db * 16) = w;
  }
}

extern "C" void kernel_launch(void* const* d_in, const int* in_sizes, int n_in,
                              void* d_out, int out_size, void* d_ws, size_t ws_size,
                              hipStream_t stream) {
  const float* x  = (const float*)d_in[0];
  const int* tp   = (const int*)d_in[1];
  const float* wq = (const float*)d_in[2];
  const float* wk = (const float*)d_in[3];
  const float* wv = (const float*)d_in[4];
  const float* wo = (const float*)d_in[5];
  float* out = (float*)d_out;

  unsigned short* ws = (unsigned short*)d_ws;
  unsigned short* xb  = ws;                   // (b,s,dm) bf16        8 MB
  unsigned short* w3b = ws + 4194304;         // [wq;wk;wv] 3072x1024 6 MB
  unsigned short* wob = ws + 7340032;         // 2 MB
  unsigned short* Qr  = ws + 8388608;         // (b,h,s,64)  8 MB
  unsigned short* Kr  = ws + 12582912;        // (b,h,s,64)  8 MB
  unsigned short* Vt  = ws + 16777216;        // (b,h,64,s-perm)  8 MB
  unsigned short* At  = ws + 20971520;        // (b,s,h*64)  8 MB

  cvt_all<<<8192, 256, 0, stream>>>(x, wq, wk, wv, wo, ws);
  gemm_qkv<<<dim3(24, 32), 256, 0, stream>>>(xb, w3b, Qr, Kr, Vt, tp);
  flash_attn<<<1024, 256, 0, stream>>>(Qr, Kr, Vt, At);
  gemm_ao<<<dim3(8, 32), 256, 0, stream>>>(At, wob, out);
}